// Round 1
// baseline (99.540 us; speedup 1.0000x reference)
//
#include <hip/hip_runtime.h>
#include <math.h>

#define NB   64
#define NC_  256
#define NH   40
#define NW   40
#define NHW  1600
#define NWIN 64

// ---------------------------------------------------------------------------
// Kernel A: window-mean pool of f2 + BN + ReLU.
// One block per (b, c). Stage image in LDS (coalesced), threads 0..63 each
// compute one 5x5 window mean. f2 = 2*feats (w<30) or feats+1e-5 (w>=30);
// each window lies entirely in one region, so apply transform to the mean.
// pooled layout: [b][win][c] (c contiguous) for kernel B's coalesced dot.
// ---------------------------------------------------------------------------
__global__ __launch_bounds__(256) void pool_bn_kernel(
    const float* __restrict__ feats,
    const float* __restrict__ gd, const float* __restrict__ bed,
    const float* __restrict__ rmd, const float* __restrict__ rvd,
    float* __restrict__ pooled)
{
    __shared__ float img[NHW];
    const int bc = blockIdx.x;          // b*256 + c
    const int b  = bc >> 8;
    const int c  = bc & 255;

    const float* src = feats + (size_t)bc * NHW;
    for (int i = threadIdx.x; i < NHW; i += 256) img[i] = src[i];
    __syncthreads();

    if (threadIdx.x < NWIN) {
        const int win = threadIdx.x;
        const int wh  = win >> 3;
        const int ww  = win & 7;
        const int base = (wh * 5) * NW + ww * 5;
        float sum = 0.f;
        #pragma unroll
        for (int i = 0; i < 5; ++i)
            #pragma unroll
            for (int j = 0; j < 5; ++j)
                sum += img[base + i * NW + j];
        float mean = sum * (1.0f / 25.0f);
        float f2m  = (ww < 6) ? (2.0f * mean) : (mean + 1e-5f);
        float inv  = gd[c] / sqrtf(rvd[c] + 1e-5f);
        float v    = f2m * inv + (bed[c] - rmd[c] * inv);
        v = fmaxf(v, 0.0f);
        pooled[((size_t)(b * NWIN + win)) * NC_ + c] = v;
    }
}

// ---------------------------------------------------------------------------
// Kernel B: co = pooled . wd^T + bd  (8 outputs per window), then the 2x3
// affine M. One block per (b, win); 256 threads = 256 channels.
// Mbuf layout: [b*64+win][6] = {M00, M01, M02, M10, M11, M12}.
// ---------------------------------------------------------------------------
__global__ __launch_bounds__(256) void co_M_kernel(
    const float* __restrict__ pooled,
    const float* __restrict__ wd, const float* __restrict__ bd,
    float* __restrict__ Mbuf)
{
    const int blk = blockIdx.x;         // b*64 + win
    const int tid = threadIdx.x;

    __shared__ float red[4][8];
    __shared__ float co[8];

    const float p = pooled[(size_t)blk * NC_ + tid];
    float part[8];
    #pragma unroll
    for (int o = 0; o < 8; ++o) part[o] = p * wd[o * NC_ + tid];

    const int lane = tid & 63;
    const int wv   = tid >> 6;
    #pragma unroll
    for (int o = 0; o < 8; ++o) {
        float v = part[o];
        #pragma unroll
        for (int off = 32; off > 0; off >>= 1) v += __shfl_down(v, off, 64);
        if (lane == 0) red[wv][o] = v;
    }
    __syncthreads();
    if (tid < 8) co[tid] = red[0][tid] + red[1][tid] + red[2][tid] + red[3][tid] + bd[tid];
    __syncthreads();

    if (tid == 0) {
        const float xr = co[0], yr = co[1], sx = co[2], sy = co[3];
        const float tx0 = co[4], tx1 = co[5], ty0 = co[6], ty1 = co[7];
        const float cx = cosf(xr), sxr = sinf(xr);
        const float cy = cosf(yr), syr = sinf(yr);
        const float s = sx * sy;
        float* m = Mbuf + blk * 6;
        m[0] = (cx * cy - sxr * syr) * s;          // M00
        m[1] = (cx * syr + sxr * cy) * s;          // M01
        m[2] = sx * (cx * ty0 + sxr * ty1) + tx0;  // M02
        m[3] = (-sxr * cy - cx * syr) * s;         // M10
        m[4] = (-sxr * syr + cx * cy) * s;         // M11
        m[5] = sx * (-sxr * ty0 + cx * ty1) + tx1; // M12
    }
}

// ---------------------------------------------------------------------------
// Kernel C: bilinear grid-sample of f2. One block per (b, c).
// Stage f2-transformed image (6.4 KB) + this batch's 64 M matrices in LDS;
// each thread computes ~6 output pixels. Global reads/writes coalesced,
// all gathers from LDS.
// ---------------------------------------------------------------------------
__global__ __launch_bounds__(256) void sample_kernel(
    const float* __restrict__ feats,
    const float* __restrict__ Mbuf,
    float* __restrict__ out)
{
    __shared__ float img[NHW];
    __shared__ float Ml[NWIN * 6];

    const int bc = blockIdx.x;          // b*256 + c
    const int b  = bc >> 8;

    const float* src = feats + (size_t)bc * NHW;
    for (int i = threadIdx.x; i < NHW; i += 256) {
        float v = src[i];
        int w = i % NW;
        img[i] = (w < 30) ? (2.0f * v) : (v + 1e-5f);
    }
    for (int i = threadIdx.x; i < NWIN * 6; i += 256)
        Ml[i] = Mbuf[b * NWIN * 6 + i];
    __syncthreads();

    float* dst = out + (size_t)bc * NHW;
    for (int idx = threadIdx.x; idx < NHW; idx += 256) {
        const int h  = idx / NW;
        const int w  = idx - h * NW;
        const int wh = h / 5, ii = h - wh * 5;
        const int ww = w / 5, jj = w - ww * 5;
        const float* m = &Ml[(wh * 8 + ww) * 6];

        const float wcx = (float)(jj - 2) * (2.0f / 39.0f);
        const float wcy = (float)(ii - 2) * (2.0f / 39.0f);
        const float gx = m[0] * wcx + m[1] * wcy + m[2];
        const float gy = m[3] * wcx + m[4] * wcy + m[5];

        float x = (gx + 1.0f) * 19.5f;
        float y = (gy + 1.0f) * 19.5f;
        // guard against pathological magnitudes before int conversion
        x = fminf(fmaxf(x, -1.0e6f), 1.0e6f);
        y = fminf(fmaxf(y, -1.0e6f), 1.0e6f);

        const float x0f = floorf(x), y0f = floorf(y);
        const int x0 = (int)x0f, y0 = (int)y0f;
        const int x1 = x0 + 1,  y1 = y0 + 1;
        const float fx = x - x0f, fy = y - y0f;

        const bool xv0 = (x0 >= 0) & (x0 <= NW - 1);
        const bool xv1 = (x1 >= 0) & (x1 <= NW - 1);
        const bool yv0 = (y0 >= 0) & (y0 <= NH - 1);
        const bool yv1 = (y1 >= 0) & (y1 <= NH - 1);

        const int xc0 = min(max(x0, 0), NW - 1);
        const int xc1 = min(max(x1, 0), NW - 1);
        const int yc0 = min(max(y0, 0), NH - 1);
        const int yc1 = min(max(y1, 0), NH - 1);

        float acc = 0.f;
        acc += img[yc0 * NW + xc0] * ((1.f - fx) * (1.f - fy)) * (float)(xv0 && yv0);
        acc += img[yc0 * NW + xc1] * (fx * (1.f - fy)) * (float)(xv1 && yv0);
        acc += img[yc1 * NW + xc0] * ((1.f - fx) * fy) * (float)(xv0 && yv1);
        acc += img[yc1 * NW + xc1] * (fx * fy) * (float)(xv1 && yv1);

        dst[idx] = acc;
    }
}

// ---------------------------------------------------------------------------
extern "C" void kernel_launch(void* const* d_in, const int* in_sizes, int n_in,
                              void* d_out, int out_size, void* d_ws, size_t ws_size,
                              hipStream_t stream)
{
    (void)in_sizes; (void)n_in; (void)out_size; (void)ws_size;

    const float* feats = (const float*)d_in[0];
    // d_in[1..8] (w1,b1,g1,be1,rm1,rv1,w2,b2) are dead code in the reference.
    const float* gd  = (const float*)d_in[9];
    const float* bed = (const float*)d_in[10];
    const float* rmd = (const float*)d_in[11];
    const float* rvd = (const float*)d_in[12];
    const float* wd  = (const float*)d_in[13];
    const float* bd  = (const float*)d_in[14];

    float* out = (float*)d_out;

    // pooled (4 MB) staged in the front of d_out — it is fully overwritten by
    // sample_kernel afterwards (stream-ordered). M coefficients in d_ws (98 KB).
    float* pooled = out;
    float* Mbuf   = (float*)d_ws;

    pool_bn_kernel<<<NB * NC_, 256, 0, stream>>>(feats, gd, bed, rmd, rvd, pooled);
    co_M_kernel<<<NB * NWIN, 256, 0, stream>>>(pooled, wd, bd, Mbuf);
    sample_kernel<<<NB * NC_, 256, 0, stream>>>(feats, Mbuf, out);
}

// Round 2
// 82.016 us; speedup vs baseline: 1.2137x; 1.2137x over previous
//
#include <hip/hip_runtime.h>
#include <math.h>

#define NB   64
#define NC_  256
#define NH   40
#define NW   40
#define NHW  1600
#define NWIN 64

// ---------------------------------------------------------------------------
// Kernel A: window-mean pool of f2 + BN + ReLU. One block per (b, c).
// float4-vectorized LDS staging; threads 0..63 each reduce one 5x5 window.
// pooled layout: [b][win][c] for kernel B's coalesced dot.
// ---------------------------------------------------------------------------
__global__ __launch_bounds__(256) void pool_bn_kernel(
    const float* __restrict__ feats,
    const float* __restrict__ gd, const float* __restrict__ bed,
    const float* __restrict__ rmd, const float* __restrict__ rvd,
    float* __restrict__ pooled)
{
    __shared__ __align__(16) float img[NHW];
    const int bc = blockIdx.x;          // b*256 + c
    const int b  = bc >> 8;
    const int c  = bc & 255;

    const float4* src4 = (const float4*)(feats + (size_t)bc * NHW);
    for (int i = threadIdx.x; i < NHW / 4; i += 256)
        ((float4*)img)[i] = src4[i];
    __syncthreads();

    if (threadIdx.x < NWIN) {
        const int win = threadIdx.x;
        const int wh  = win >> 3;
        const int ww  = win & 7;
        const int base = (wh * 5) * NW + ww * 5;
        float sum = 0.f;
        #pragma unroll
        for (int i = 0; i < 5; ++i)
            #pragma unroll
            for (int j = 0; j < 5; ++j)
                sum += img[base + i * NW + j];
        float mean = sum * (1.0f / 25.0f);
        float f2m  = (ww < 6) ? (2.0f * mean) : (mean + 1e-5f);
        float inv  = gd[c] / sqrtf(rvd[c] + 1e-5f);
        float v    = f2m * inv + (bed[c] - rmd[c] * inv);
        v = fmaxf(v, 0.0f);
        pooled[((size_t)(b * NWIN + win)) * NC_ + c] = v;
    }
}

// ---------------------------------------------------------------------------
// Kernel B: co = pooled . wd^T + bd, affine M, AND per-pixel bilinear
// coefficients for this window's 25 pixels (threads 0..24).
// cw4[b*1600+px] = 4 weights (validity folded); cpk[b*1600+px] = 4 packed
// gather positions (16 bits each, already clamped, y*40+x).
// ---------------------------------------------------------------------------
__global__ __launch_bounds__(256) void co_M_kernel(
    const float* __restrict__ pooled,
    const float* __restrict__ wd, const float* __restrict__ bd,
    float* __restrict__ Mbuf,
    float4* __restrict__ cw4, uint2* __restrict__ cpk)
{
    const int blk = blockIdx.x;         // b*64 + win
    const int tid = threadIdx.x;

    __shared__ float red[4][8];
    __shared__ float co[8];
    __shared__ float sM[6];

    const float p = pooled[(size_t)blk * NC_ + tid];
    float part[8];
    #pragma unroll
    for (int o = 0; o < 8; ++o) part[o] = p * wd[o * NC_ + tid];

    const int lane = tid & 63;
    const int wv   = tid >> 6;
    #pragma unroll
    for (int o = 0; o < 8; ++o) {
        float v = part[o];
        #pragma unroll
        for (int off = 32; off > 0; off >>= 1) v += __shfl_down(v, off, 64);
        if (lane == 0) red[wv][o] = v;
    }
    __syncthreads();
    if (tid < 8) co[tid] = red[0][tid] + red[1][tid] + red[2][tid] + red[3][tid] + bd[tid];
    __syncthreads();

    if (tid == 0) {
        const float xr = co[0], yr = co[1], sx = co[2], sy = co[3];
        const float tx0 = co[4], tx1 = co[5], ty0 = co[6], ty1 = co[7];
        const float cx = cosf(xr), sxr = sinf(xr);
        const float cy = cosf(yr), syr = sinf(yr);
        const float s = sx * sy;
        float* m = Mbuf + blk * 6;
        sM[0] = m[0] = (cx * cy - sxr * syr) * s;          // M00
        sM[1] = m[1] = (cx * syr + sxr * cy) * s;          // M01
        sM[2] = m[2] = sx * (cx * ty0 + sxr * ty1) + tx0;  // M02
        sM[3] = m[3] = (-sxr * cy - cx * syr) * s;         // M10
        sM[4] = m[4] = (-sxr * syr + cx * cy) * s;         // M11
        sM[5] = m[5] = sx * (-sxr * ty0 + cx * ty1) + tx1; // M12
    }
    __syncthreads();

    if (cw4 != nullptr && tid < 25) {
        const int b   = blk >> 6;
        const int win = blk & 63;
        const int wh  = win >> 3;
        const int ww  = win & 7;
        const int ii  = tid / 5;
        const int jj  = tid - ii * 5;

        const float wcx = (float)(jj - 2) * (2.0f / 39.0f);
        const float wcy = (float)(ii - 2) * (2.0f / 39.0f);
        const float gx = sM[0] * wcx + sM[1] * wcy + sM[2];
        const float gy = sM[3] * wcx + sM[4] * wcy + sM[5];

        float x = (gx + 1.0f) * 19.5f;
        float y = (gy + 1.0f) * 19.5f;
        x = fminf(fmaxf(x, -1.0e6f), 1.0e6f);
        y = fminf(fmaxf(y, -1.0e6f), 1.0e6f);

        const float x0f = floorf(x), y0f = floorf(y);
        const int x0 = (int)x0f, y0 = (int)y0f;
        const int x1 = x0 + 1,  y1 = y0 + 1;
        const float fx = x - x0f, fy = y - y0f;

        const bool xv0 = (x0 >= 0) & (x0 <= NW - 1);
        const bool xv1 = (x1 >= 0) & (x1 <= NW - 1);
        const bool yv0 = (y0 >= 0) & (y0 <= NH - 1);
        const bool yv1 = (y1 >= 0) & (y1 <= NH - 1);

        const int xc0 = min(max(x0, 0), NW - 1);
        const int xc1 = min(max(x1, 0), NW - 1);
        const int yc0 = min(max(y0, 0), NH - 1);
        const int yc1 = min(max(y1, 0), NH - 1);

        float4 wvec;
        wvec.x = (1.f - fx) * (1.f - fy) * (float)(xv0 && yv0);
        wvec.y = fx * (1.f - fy) * (float)(xv1 && yv0);
        wvec.z = (1.f - fx) * fy * (float)(xv0 && yv1);
        wvec.w = fx * fy * (float)(xv1 && yv1);

        uint2 pk;
        pk.x = (unsigned)(yc0 * NW + xc0) | ((unsigned)(yc0 * NW + xc1) << 16);
        pk.y = (unsigned)(yc1 * NW + xc0) | ((unsigned)(yc1 * NW + xc1) << 16);

        const int h = wh * 5 + ii;
        const int w = ww * 5 + jj;
        const int pidx = b * NHW + h * NW + w;
        cw4[pidx] = wvec;
        cpk[pidx] = pk;
    }
}

// ---------------------------------------------------------------------------
// Kernel C (fast): bilinear sample from precomputed coefficients.
// One block per (b, c), 320 threads -> exactly 5 pixels/thread.
// ---------------------------------------------------------------------------
__global__ __launch_bounds__(320) void sample_fast_kernel(
    const float* __restrict__ feats,
    const float4* __restrict__ cw4, const uint2* __restrict__ cpk,
    float* __restrict__ out)
{
    __shared__ __align__(16) float img[NHW];

    const int bc = blockIdx.x;          // b*256 + c
    const int b  = bc >> 8;

    const float4* src4 = (const float4*)(feats + (size_t)bc * NHW);
    for (int i = threadIdx.x; i < NHW / 4; i += 320) {
        float4 v = src4[i];
        const int j = i % (NW / 4);      // float4 index within row: w = 4j..4j+3
        if (j < 7)      { v.x *= 2.f; v.y *= 2.f; v.z *= 2.f; v.w *= 2.f; }
        else if (j == 7){ v.x *= 2.f; v.y *= 2.f; v.z += 1e-5f; v.w += 1e-5f; }
        else            { v.x += 1e-5f; v.y += 1e-5f; v.z += 1e-5f; v.w += 1e-5f; }
        ((float4*)img)[i] = v;
    }
    __syncthreads();

    const float4* cwb = cw4 + (size_t)b * NHW;
    const uint2*  cpb = cpk + (size_t)b * NHW;
    float* dst = out + (size_t)bc * NHW;

    #pragma unroll
    for (int k = 0; k < 5; ++k) {
        const int idx = k * 320 + threadIdx.x;
        const float4 wv = cwb[idx];
        const uint2  pk = cpb[idx];
        const int p00 = pk.x & 0xffff, p01 = pk.x >> 16;
        const int p10 = pk.y & 0xffff, p11 = pk.y >> 16;
        dst[idx] = wv.x * img[p00] + wv.y * img[p01]
                 + wv.z * img[p10] + wv.w * img[p11];
    }
}

// ---------------------------------------------------------------------------
// Kernel C (fallback, round-1 version): used only if ws_size is too small
// for the coefficient buffers.
// ---------------------------------------------------------------------------
__global__ __launch_bounds__(256) void sample_kernel(
    const float* __restrict__ feats,
    const float* __restrict__ Mbuf,
    float* __restrict__ out)
{
    __shared__ __align__(16) float img[NHW];
    __shared__ float Ml[NWIN * 6];

    const int bc = blockIdx.x;
    const int b  = bc >> 8;

    const float4* src4 = (const float4*)(feats + (size_t)bc * NHW);
    for (int i = threadIdx.x; i < NHW / 4; i += 256) {
        float4 v = src4[i];
        const int j = i % (NW / 4);
        if (j < 7)      { v.x *= 2.f; v.y *= 2.f; v.z *= 2.f; v.w *= 2.f; }
        else if (j == 7){ v.x *= 2.f; v.y *= 2.f; v.z += 1e-5f; v.w += 1e-5f; }
        else            { v.x += 1e-5f; v.y += 1e-5f; v.z += 1e-5f; v.w += 1e-5f; }
        ((float4*)img)[i] = v;
    }
    for (int i = threadIdx.x; i < NWIN * 6; i += 256)
        Ml[i] = Mbuf[b * NWIN * 6 + i];
    __syncthreads();

    float* dst = out + (size_t)bc * NHW;
    for (int idx = threadIdx.x; idx < NHW; idx += 256) {
        const int h  = idx / NW;
        const int w  = idx - h * NW;
        const int wh = h / 5, ii = h - wh * 5;
        const int ww = w / 5, jj = w - ww * 5;
        const float* m = &Ml[(wh * 8 + ww) * 6];

        const float wcx = (float)(jj - 2) * (2.0f / 39.0f);
        const float wcy = (float)(ii - 2) * (2.0f / 39.0f);
        const float gx = m[0] * wcx + m[1] * wcy + m[2];
        const float gy = m[3] * wcx + m[4] * wcy + m[5];

        float x = (gx + 1.0f) * 19.5f;
        float y = (gy + 1.0f) * 19.5f;
        x = fminf(fmaxf(x, -1.0e6f), 1.0e6f);
        y = fminf(fmaxf(y, -1.0e6f), 1.0e6f);

        const float x0f = floorf(x), y0f = floorf(y);
        const int x0 = (int)x0f, y0 = (int)y0f;
        const int x1 = x0 + 1,  y1 = y0 + 1;
        const float fx = x - x0f, fy = y - y0f;

        const bool xv0 = (x0 >= 0) & (x0 <= NW - 1);
        const bool xv1 = (x1 >= 0) & (x1 <= NW - 1);
        const bool yv0 = (y0 >= 0) & (y0 <= NH - 1);
        const bool yv1 = (y1 >= 0) & (y1 <= NH - 1);

        const int xc0 = min(max(x0, 0), NW - 1);
        const int xc1 = min(max(x1, 0), NW - 1);
        const int yc0 = min(max(y0, 0), NH - 1);
        const int yc1 = min(max(y1, 0), NH - 1);

        float acc = 0.f;
        acc += img[yc0 * NW + xc0] * ((1.f - fx) * (1.f - fy)) * (float)(xv0 && yv0);
        acc += img[yc0 * NW + xc1] * (fx * (1.f - fy)) * (float)(xv1 && yv0);
        acc += img[yc1 * NW + xc0] * ((1.f - fx) * fy) * (float)(xv0 && yv1);
        acc += img[yc1 * NW + xc1] * (fx * fy) * (float)(xv1 && yv1);

        dst[idx] = acc;
    }
}

// ---------------------------------------------------------------------------
extern "C" void kernel_launch(void* const* d_in, const int* in_sizes, int n_in,
                              void* d_out, int out_size, void* d_ws, size_t ws_size,
                              hipStream_t stream)
{
    (void)in_sizes; (void)n_in; (void)out_size;

    const float* feats = (const float*)d_in[0];
    // d_in[1..8] (w1,b1,g1,be1,rm1,rv1,w2,b2) are dead code in the reference.
    const float* gd  = (const float*)d_in[9];
    const float* bed = (const float*)d_in[10];
    const float* rmd = (const float*)d_in[11];
    const float* rvd = (const float*)d_in[12];
    const float* wd  = (const float*)d_in[13];
    const float* bd  = (const float*)d_in[14];

    float* out = (float*)d_out;

    // pooled (4 MB) staged in the front of d_out — fully overwritten by the
    // sample kernel afterwards (stream-ordered).
    float* pooled = out;

    // d_ws layout: Mbuf [96 KB] | cw4 [1.6 MB, 16B-aligned] | cpk [0.8 MB]
    const size_t MBUF_B = (size_t)NB * NWIN * 6 * sizeof(float);      // 98304
    const size_t CW_OFF = 98304;                                      // 16-aligned
    const size_t CW_B   = (size_t)NB * NHW * sizeof(float4);          // 1638400
    const size_t PK_OFF = CW_OFF + CW_B;                              // 1736704
    const size_t PK_B   = (size_t)NB * NHW * sizeof(uint2);           // 819200
    const bool fast = (ws_size >= PK_OFF + PK_B) && (MBUF_B <= CW_OFF);

    float*  Mbuf = (float*)d_ws;
    float4* cw4  = fast ? (float4*)((char*)d_ws + CW_OFF) : nullptr;
    uint2*  cpk  = fast ? (uint2*)((char*)d_ws + PK_OFF)  : nullptr;

    pool_bn_kernel<<<NB * NC_, 256, 0, stream>>>(feats, gd, bed, rmd, rvd, pooled);
    co_M_kernel<<<NB * NWIN, 256, 0, stream>>>(pooled, wd, bd, Mbuf, cw4, cpk);
    if (fast)
        sample_fast_kernel<<<NB * NC_, 320, 0, stream>>>(feats, cw4, cpk, out);
    else
        sample_kernel<<<NB * NC_, 256, 0, stream>>>(feats, Mbuf, out);
}

// Round 3
// 78.984 us; speedup vs baseline: 1.2603x; 1.0384x over previous
//
#include <hip/hip_runtime.h>
#include <math.h>

#define NB   64
#define NC_  256
#define NH   40
#define NW   40
#define NHW  1600
#define NWIN 64
#define CH   8          // channels per sample block
#define IMS  1608       // padded per-channel LDS stride (floats); 1608&31 == 8

// ---------------------------------------------------------------------------
// Kernel A: window-mean pool of f2 + BN + ReLU. One block per (b, c).
// float4-vectorized LDS staging; threads 0..63 each reduce one 5x5 window.
// pooled layout: [b][win][c] for kernel B's coalesced dot.
// ---------------------------------------------------------------------------
__global__ __launch_bounds__(256) void pool_bn_kernel(
    const float* __restrict__ feats,
    const float* __restrict__ gd, const float* __restrict__ bed,
    const float* __restrict__ rmd, const float* __restrict__ rvd,
    float* __restrict__ pooled)
{
    __shared__ __align__(16) float img[NHW];
    const int bc = blockIdx.x;          // b*256 + c
    const int b  = bc >> 8;
    const int c  = bc & 255;

    const float4* src4 = (const float4*)(feats + (size_t)bc * NHW);
    for (int i = threadIdx.x; i < NHW / 4; i += 256)
        ((float4*)img)[i] = src4[i];
    __syncthreads();

    if (threadIdx.x < NWIN) {
        const int win = threadIdx.x;
        const int wh  = win >> 3;
        const int ww  = win & 7;
        const int base = (wh * 5) * NW + ww * 5;
        float sum = 0.f;
        #pragma unroll
        for (int i = 0; i < 5; ++i)
            #pragma unroll
            for (int j = 0; j < 5; ++j)
                sum += img[base + i * NW + j];
        float mean = sum * (1.0f / 25.0f);
        float f2m  = (ww < 6) ? (2.0f * mean) : (mean + 1e-5f);
        float inv  = gd[c] / sqrtf(rvd[c] + 1e-5f);
        float v    = f2m * inv + (bed[c] - rmd[c] * inv);
        v = fmaxf(v, 0.0f);
        pooled[((size_t)(b * NWIN + win)) * NC_ + c] = v;
    }
}

// ---------------------------------------------------------------------------
// Kernel B: co = pooled . wd^T + bd, affine M, AND per-pixel bilinear
// coefficients for this window's 25 pixels (threads 0..24).
// cw4[b*1600+px] = 4 weights (validity folded); cpk[b*1600+px] = 4 packed
// gather positions (16 bits each, already clamped, y*40+x).
// ---------------------------------------------------------------------------
__global__ __launch_bounds__(256) void co_M_kernel(
    const float* __restrict__ pooled,
    const float* __restrict__ wd, const float* __restrict__ bd,
    float* __restrict__ Mbuf,
    float4* __restrict__ cw4, uint2* __restrict__ cpk)
{
    const int blk = blockIdx.x;         // b*64 + win
    const int tid = threadIdx.x;

    __shared__ float red[4][8];
    __shared__ float co[8];
    __shared__ float sM[6];

    const float p = pooled[(size_t)blk * NC_ + tid];
    float part[8];
    #pragma unroll
    for (int o = 0; o < 8; ++o) part[o] = p * wd[o * NC_ + tid];

    const int lane = tid & 63;
    const int wv   = tid >> 6;
    #pragma unroll
    for (int o = 0; o < 8; ++o) {
        float v = part[o];
        #pragma unroll
        for (int off = 32; off > 0; off >>= 1) v += __shfl_down(v, off, 64);
        if (lane == 0) red[wv][o] = v;
    }
    __syncthreads();
    if (tid < 8) co[tid] = red[0][tid] + red[1][tid] + red[2][tid] + red[3][tid] + bd[tid];
    __syncthreads();

    if (tid == 0) {
        const float xr = co[0], yr = co[1], sx = co[2], sy = co[3];
        const float tx0 = co[4], tx1 = co[5], ty0 = co[6], ty1 = co[7];
        const float cx = cosf(xr), sxr = sinf(xr);
        const float cy = cosf(yr), syr = sinf(yr);
        const float s = sx * sy;
        float* m = Mbuf + blk * 6;
        sM[0] = m[0] = (cx * cy - sxr * syr) * s;          // M00
        sM[1] = m[1] = (cx * syr + sxr * cy) * s;          // M01
        sM[2] = m[2] = sx * (cx * ty0 + sxr * ty1) + tx0;  // M02
        sM[3] = m[3] = (-sxr * cy - cx * syr) * s;         // M10
        sM[4] = m[4] = (-sxr * syr + cx * cy) * s;         // M11
        sM[5] = m[5] = sx * (-sxr * ty0 + cx * ty1) + tx1; // M12
    }
    __syncthreads();

    if (cw4 != nullptr && tid < 25) {
        const int b   = blk >> 6;
        const int win = blk & 63;
        const int wh  = win >> 3;
        const int ww  = win & 7;
        const int ii  = tid / 5;
        const int jj  = tid - ii * 5;

        const float wcx = (float)(jj - 2) * (2.0f / 39.0f);
        const float wcy = (float)(ii - 2) * (2.0f / 39.0f);
        const float gx = sM[0] * wcx + sM[1] * wcy + sM[2];
        const float gy = sM[3] * wcx + sM[4] * wcy + sM[5];

        float x = (gx + 1.0f) * 19.5f;
        float y = (gy + 1.0f) * 19.5f;
        x = fminf(fmaxf(x, -1.0e6f), 1.0e6f);
        y = fminf(fmaxf(y, -1.0e6f), 1.0e6f);

        const float x0f = floorf(x), y0f = floorf(y);
        const int x0 = (int)x0f, y0 = (int)y0f;
        const int x1 = x0 + 1,  y1 = y0 + 1;
        const float fx = x - x0f, fy = y - y0f;

        const bool xv0 = (x0 >= 0) & (x0 <= NW - 1);
        const bool xv1 = (x1 >= 0) & (x1 <= NW - 1);
        const bool yv0 = (y0 >= 0) & (y0 <= NH - 1);
        const bool yv1 = (y1 >= 0) & (y1 <= NH - 1);

        const int xc0 = min(max(x0, 0), NW - 1);
        const int xc1 = min(max(x1, 0), NW - 1);
        const int yc0 = min(max(y0, 0), NH - 1);
        const int yc1 = min(max(y1, 0), NH - 1);

        float4 wvec;
        wvec.x = (1.f - fx) * (1.f - fy) * (float)(xv0 && yv0);
        wvec.y = fx * (1.f - fy) * (float)(xv1 && yv0);
        wvec.z = (1.f - fx) * fy * (float)(xv0 && yv1);
        wvec.w = fx * fy * (float)(xv1 && yv1);

        uint2 pk;
        pk.x = (unsigned)(yc0 * NW + xc0) | ((unsigned)(yc0 * NW + xc1) << 16);
        pk.y = (unsigned)(yc1 * NW + xc0) | ((unsigned)(yc1 * NW + xc1) << 16);

        const int h = wh * 5 + ii;
        const int w = ww * 5 + jj;
        const int pidx = b * NHW + h * NW + w;
        cw4[pidx] = wvec;
        cpk[pidx] = pk;
    }
}

// ---------------------------------------------------------------------------
// Kernel C: bilinear sample, CH=8 channels per block. One block per
// (b, cgroup); 320 threads -> 5 pixels/thread; coefficient load amortized
// over 8 channels. LDS: 8 padded f2-images (51.5 KB).
// ---------------------------------------------------------------------------
__global__ __launch_bounds__(320) void sample_multi_kernel(
    const float* __restrict__ feats,
    const float4* __restrict__ cw4, const uint2* __restrict__ cpk,
    float* __restrict__ out)
{
    __shared__ __align__(16) float img[CH][IMS];

    const int blk = blockIdx.x;         // b*32 + cg
    const int b   = blk >> 5;
    const int cg  = blk & 31;
    const int c0  = cg * CH;

    // stage CH images, f2-transformed. CH*400 float4 = 3200 -> 10 per thread.
    for (int i = threadIdx.x; i < CH * (NHW / 4); i += 320) {
        const int cc = i / (NHW / 4);
        const int v4 = i - cc * (NHW / 4);
        float4 v = ((const float4*)(feats + (size_t)(b * NC_ + c0 + cc) * NHW))[v4];
        const int j = v4 % (NW / 4);     // float4 index within row
        if (j < 7)      { v.x *= 2.f; v.y *= 2.f; v.z *= 2.f; v.w *= 2.f; }
        else if (j == 7){ v.x *= 2.f; v.y *= 2.f; v.z += 1e-5f; v.w += 1e-5f; }
        else            { v.x += 1e-5f; v.y += 1e-5f; v.z += 1e-5f; v.w += 1e-5f; }
        *(float4*)&img[cc][v4 * 4] = v;
    }
    __syncthreads();

    const float4* cwb = cw4 + (size_t)b * NHW;
    const uint2*  cpb = cpk + (size_t)b * NHW;
    float* dstb = out + (size_t)(b * NC_ + c0) * NHW;

    #pragma unroll
    for (int k = 0; k < 5; ++k) {
        const int p = k * 320 + threadIdx.x;
        const float4 wv = cwb[p];
        const uint2  pk = cpb[p];
        const int p00 = pk.x & 0xffff, p01 = pk.x >> 16;
        const int p10 = pk.y & 0xffff, p11 = pk.y >> 16;
        #pragma unroll
        for (int cc = 0; cc < CH; ++cc) {
            const float r = wv.x * img[cc][p00] + wv.y * img[cc][p01]
                          + wv.z * img[cc][p10] + wv.w * img[cc][p11];
            dstb[(size_t)cc * NHW + p] = r;
        }
    }
}

// ---------------------------------------------------------------------------
// Fallback sampler (round-1 style) if ws_size is too small for coeffs.
// ---------------------------------------------------------------------------
__global__ __launch_bounds__(256) void sample_kernel(
    const float* __restrict__ feats,
    const float* __restrict__ Mbuf,
    float* __restrict__ out)
{
    __shared__ __align__(16) float img[NHW];
    __shared__ float Ml[NWIN * 6];

    const int bc = blockIdx.x;
    const int b  = bc >> 8;

    const float4* src4 = (const float4*)(feats + (size_t)bc * NHW);
    for (int i = threadIdx.x; i < NHW / 4; i += 256) {
        float4 v = src4[i];
        const int j = i % (NW / 4);
        if (j < 7)      { v.x *= 2.f; v.y *= 2.f; v.z *= 2.f; v.w *= 2.f; }
        else if (j == 7){ v.x *= 2.f; v.y *= 2.f; v.z += 1e-5f; v.w += 1e-5f; }
        else            { v.x += 1e-5f; v.y += 1e-5f; v.z += 1e-5f; v.w += 1e-5f; }
        ((float4*)img)[i] = v;
    }
    for (int i = threadIdx.x; i < NWIN * 6; i += 256)
        Ml[i] = Mbuf[b * NWIN * 6 + i];
    __syncthreads();

    float* dst = out + (size_t)bc * NHW;
    for (int idx = threadIdx.x; idx < NHW; idx += 256) {
        const int h  = idx / NW;
        const int w  = idx - h * NW;
        const int wh = h / 5, ii = h - wh * 5;
        const int ww = w / 5, jj = w - ww * 5;
        const float* m = &Ml[(wh * 8 + ww) * 6];

        const float wcx = (float)(jj - 2) * (2.0f / 39.0f);
        const float wcy = (float)(ii - 2) * (2.0f / 39.0f);
        const float gx = m[0] * wcx + m[1] * wcy + m[2];
        const float gy = m[3] * wcx + m[4] * wcy + m[5];

        float x = (gx + 1.0f) * 19.5f;
        float y = (gy + 1.0f) * 19.5f;
        x = fminf(fmaxf(x, -1.0e6f), 1.0e6f);
        y = fminf(fmaxf(y, -1.0e6f), 1.0e6f);

        const float x0f = floorf(x), y0f = floorf(y);
        const int x0 = (int)x0f, y0 = (int)y0f;
        const int x1 = x0 + 1,  y1 = y0 + 1;
        const float fx = x - x0f, fy = y - y0f;

        const bool xv0 = (x0 >= 0) & (x0 <= NW - 1);
        const bool xv1 = (x1 >= 0) & (x1 <= NW - 1);
        const bool yv0 = (y0 >= 0) & (y0 <= NH - 1);
        const bool yv1 = (y1 >= 0) & (y1 <= NH - 1);

        const int xc0 = min(max(x0, 0), NW - 1);
        const int xc1 = min(max(x1, 0), NW - 1);
        const int yc0 = min(max(y0, 0), NH - 1);
        const int yc1 = min(max(y1, 0), NH - 1);

        float acc = 0.f;
        acc += img[yc0 * NW + xc0] * ((1.f - fx) * (1.f - fy)) * (float)(xv0 && yv0);
        acc += img[yc0 * NW + xc1] * (fx * (1.f - fy)) * (float)(xv1 && yv0);
        acc += img[yc1 * NW + xc0] * ((1.f - fx) * fy) * (float)(xv0 && yv1);
        acc += img[yc1 * NW + xc1] * (fx * fy) * (float)(xv1 && yv1);

        dst[idx] = acc;
    }
}

// ---------------------------------------------------------------------------
extern "C" void kernel_launch(void* const* d_in, const int* in_sizes, int n_in,
                              void* d_out, int out_size, void* d_ws, size_t ws_size,
                              hipStream_t stream)
{
    (void)in_sizes; (void)n_in; (void)out_size;

    const float* feats = (const float*)d_in[0];
    // d_in[1..8] (w1,b1,g1,be1,rm1,rv1,w2,b2) are dead code in the reference.
    const float* gd  = (const float*)d_in[9];
    const float* bed = (const float*)d_in[10];
    const float* rmd = (const float*)d_in[11];
    const float* rvd = (const float*)d_in[12];
    const float* wd  = (const float*)d_in[13];
    const float* bd  = (const float*)d_in[14];

    float* out = (float*)d_out;

    // pooled (4 MB) staged in the front of d_out — fully overwritten by the
    // sample kernel afterwards (stream-ordered).
    float* pooled = out;

    // d_ws layout: Mbuf [96 KB] | cw4 [1.6 MB, 16B-aligned] | cpk [0.8 MB]
    const size_t CW_OFF = 98304;
    const size_t CW_B   = (size_t)NB * NHW * sizeof(float4);          // 1638400
    const size_t PK_OFF = CW_OFF + CW_B;                              // 1736704
    const size_t PK_B   = (size_t)NB * NHW * sizeof(uint2);           // 819200
    const bool fast = (ws_size >= PK_OFF + PK_B);

    float*  Mbuf = (float*)d_ws;
    float4* cw4  = fast ? (float4*)((char*)d_ws + CW_OFF) : nullptr;
    uint2*  cpk  = fast ? (uint2*)((char*)d_ws + PK_OFF)  : nullptr;

    pool_bn_kernel<<<NB * NC_, 256, 0, stream>>>(feats, gd, bed, rmd, rvd, pooled);
    co_M_kernel<<<NB * NWIN, 256, 0, stream>>>(pooled, wd, bd, Mbuf, cw4, cpk);
    if (fast)
        sample_multi_kernel<<<NB * (NC_ / CH), 320, 0, stream>>>(feats, cw4, cpk, out);
    else
        sample_kernel<<<NB * NC_, 256, 0, stream>>>(feats, Mbuf, out);
}

// Round 5
// 75.556 us; speedup vs baseline: 1.3174x; 1.0454x over previous
//
#include <hip/hip_runtime.h>
#include <math.h>

#define NB   64
#define NC_  256
#define NH   40
#define NW   40
#define NHW  1600
#define NWIN 64
#define CH   4          // channels per sample block
#define PW   42         // padded image width/height (border of 1, zeroed)
#define IMS  1792       // padded per-channel LDS stride in floats (>= 42*42=1764)

typedef float f32x4 __attribute__((ext_vector_type(4)));

// ---------------------------------------------------------------------------
// Kernel A: window-mean pool of f2 + BN + ReLU. One block per (b, c).
// ---------------------------------------------------------------------------
__global__ __launch_bounds__(256) void pool_bn_kernel(
    const float* __restrict__ feats,
    const float* __restrict__ gd, const float* __restrict__ bed,
    const float* __restrict__ rmd, const float* __restrict__ rvd,
    float* __restrict__ pooled)
{
    __shared__ __align__(16) float img[NHW];
    const int bc = blockIdx.x;          // b*256 + c
    const int b  = bc >> 8;
    const int c  = bc & 255;

    const float4* src4 = (const float4*)(feats + (size_t)bc * NHW);
    for (int i = threadIdx.x; i < NHW / 4; i += 256)
        ((float4*)img)[i] = src4[i];
    __syncthreads();

    if (threadIdx.x < NWIN) {
        const int win = threadIdx.x;
        const int wh  = win >> 3;
        const int ww  = win & 7;
        const int base = (wh * 5) * NW + ww * 5;
        float sum = 0.f;
        #pragma unroll
        for (int i = 0; i < 5; ++i)
            #pragma unroll
            for (int j = 0; j < 5; ++j)
                sum += img[base + i * NW + j];
        float mean = sum * (1.0f / 25.0f);
        float f2m  = (ww < 6) ? (2.0f * mean) : (mean + 1e-5f);
        float inv  = gd[c] / sqrtf(rvd[c] + 1e-5f);
        float v    = f2m * inv + (bed[c] - rmd[c] * inv);
        v = fmaxf(v, 0.0f);
        pooled[((size_t)(b * NWIN + win)) * NC_ + c] = v;
    }
}

// ---------------------------------------------------------------------------
// Kernel B: co = pooled . wd^T + bd, affine M, and per-pixel bilinear
// coefficients: cw4[b*1600+px] = 4 validity-folded weights;
// cbase[b*1600+px] = base index into the 42x42 zero-bordered padded image
// (corners at base, base+1, base+42, base+43).
// ---------------------------------------------------------------------------
__global__ __launch_bounds__(256) void co_M_kernel(
    const float* __restrict__ pooled,
    const float* __restrict__ wd, const float* __restrict__ bd,
    float* __restrict__ Mbuf,
    float4* __restrict__ cw4, unsigned* __restrict__ cbase)
{
    const int blk = blockIdx.x;         // b*64 + win
    const int tid = threadIdx.x;

    __shared__ float red[4][8];
    __shared__ float co[8];
    __shared__ float sM[6];

    const float p = pooled[(size_t)blk * NC_ + tid];
    float part[8];
    #pragma unroll
    for (int o = 0; o < 8; ++o) part[o] = p * wd[o * NC_ + tid];

    const int lane = tid & 63;
    const int wv   = tid >> 6;
    #pragma unroll
    for (int o = 0; o < 8; ++o) {
        float v = part[o];
        #pragma unroll
        for (int off = 32; off > 0; off >>= 1) v += __shfl_down(v, off, 64);
        if (lane == 0) red[wv][o] = v;
    }
    __syncthreads();
    if (tid < 8) co[tid] = red[0][tid] + red[1][tid] + red[2][tid] + red[3][tid] + bd[tid];
    __syncthreads();

    if (tid == 0) {
        const float xr = co[0], yr = co[1], sx = co[2], sy = co[3];
        const float tx0 = co[4], tx1 = co[5], ty0 = co[6], ty1 = co[7];
        const float cx = cosf(xr), sxr = sinf(xr);
        const float cy = cosf(yr), syr = sinf(yr);
        const float s = sx * sy;
        float* m = Mbuf + blk * 6;
        sM[0] = m[0] = (cx * cy - sxr * syr) * s;          // M00
        sM[1] = m[1] = (cx * syr + sxr * cy) * s;          // M01
        sM[2] = m[2] = sx * (cx * ty0 + sxr * ty1) + tx0;  // M02
        sM[3] = m[3] = (-sxr * cy - cx * syr) * s;         // M10
        sM[4] = m[4] = (-sxr * syr + cx * cy) * s;         // M11
        sM[5] = m[5] = sx * (-sxr * ty0 + cx * ty1) + tx1; // M12
    }
    __syncthreads();

    if (cw4 != nullptr && tid < 25) {
        const int b   = blk >> 6;
        const int win = blk & 63;
        const int wh  = win >> 3;
        const int ww  = win & 7;
        const int ii  = tid / 5;
        const int jj  = tid - ii * 5;

        const float wcx = (float)(jj - 2) * (2.0f / 39.0f);
        const float wcy = (float)(ii - 2) * (2.0f / 39.0f);
        const float gx = sM[0] * wcx + sM[1] * wcy + sM[2];
        const float gy = sM[3] * wcx + sM[4] * wcy + sM[5];

        float x = (gx + 1.0f) * 19.5f;
        float y = (gy + 1.0f) * 19.5f;
        x = fminf(fmaxf(x, -1.0e6f), 1.0e6f);
        y = fminf(fmaxf(y, -1.0e6f), 1.0e6f);

        const float x0f = floorf(x), y0f = floorf(y);
        const int x0 = (int)x0f, y0 = (int)y0f;
        const int x1 = x0 + 1,  y1 = y0 + 1;
        const float fx = x - x0f, fy = y - y0f;

        const bool xv0 = (x0 >= 0) & (x0 <= NW - 1);
        const bool xv1 = (x1 >= 0) & (x1 <= NW - 1);
        const bool yv0 = (y0 >= 0) & (y0 <= NH - 1);
        const bool yv1 = (y1 >= 0) & (y1 <= NH - 1);

        float4 wvec;
        wvec.x = (1.f - fx) * (1.f - fy) * (float)(xv0 && yv0);
        wvec.y = fx * (1.f - fy) * (float)(xv1 && yv0);
        wvec.z = (1.f - fx) * fy * (float)(xv0 && yv1);
        wvec.w = fx * fy * (float)(xv1 && yv1);

        // clamped base into 42x42 padded image; corners base,+1,+42,+43 all
        // in-range (rows/cols 0..41); invalid corners carry weight 0 and the
        // border cells are zeroed.
        const int xb = min(max(x0, -1), NW - 1);
        const int yb = min(max(y0, -1), NH - 1);
        const unsigned base = (unsigned)((yb + 1) * PW + (xb + 1));

        const int h = wh * 5 + ii;
        const int w = ww * 5 + jj;
        const int pidx = b * NHW + h * NW + w;
        cw4[pidx]   = wvec;
        cbase[pidx] = base;
    }
}

// ---------------------------------------------------------------------------
// Kernel C: bilinear sample, CH=4 channels per block, 42x42 zero-bordered
// padded LDS images. One block per (b, cgroup); 320 threads, 5 px/thread.
// Corners at base,+1,+42,+43 -> ds_read2-mergeable row pairs.
// ---------------------------------------------------------------------------
__global__ __launch_bounds__(320) void sample_pad_kernel(
    const float* __restrict__ feats,
    const float4* __restrict__ cw4, const unsigned* __restrict__ cbase,
    float* __restrict__ out)
{
    __shared__ float img[CH * IMS];

    const int blk = blockIdx.x;         // b*(256/CH) + cg
    const int b   = blk >> 6;           // 256/CH = 64
    const int cg  = blk & 63;
    const int c0  = cg * CH;

    // zero the borders (164 cells per channel); interior is fully overwritten.
    for (int i = threadIdx.x; i < CH * 164; i += 320) {
        const int cc = i / 164;
        const int t  = i - cc * 164;
        int addr;
        if (t < 42)       addr = t;                         // top row
        else if (t < 84)  addr = 41 * PW + (t - 42);        // bottom row
        else if (t < 124) addr = (t - 84 + 1) * PW;         // left col rows 1..40
        else              addr = (t - 124 + 1) * PW + 41;   // right col rows 1..40
        img[cc * IMS + addr] = 0.f;
    }

    // stage CH f2-transformed images into the padded interior.
    for (int i = threadIdx.x; i < CH * (NHW / 4); i += 320) {
        const int cc = i / (NHW / 4);
        const int v4 = i - cc * (NHW / 4);
        const f32x4 v = __builtin_nontemporal_load(
            (const f32x4*)(feats + (size_t)(b * NC_ + c0 + cc) * NHW) + v4);
        const int p0 = v4 * 4;
        #pragma unroll
        for (int k = 0; k < 4; ++k) {
            const int p   = p0 + k;
            const int r   = p / NW;
            const int col = p - r * NW;
            const float t = (col < 30) ? (2.0f * v[k]) : (v[k] + 1e-5f);
            img[cc * IMS + (r + 1) * PW + col + 1] = t;
        }
    }
    __syncthreads();

    const float4*   cwb = cw4   + (size_t)b * NHW;
    const unsigned* cbb = cbase + (size_t)b * NHW;
    float* dstb = out + (size_t)(b * NC_ + c0) * NHW;

    #pragma unroll
    for (int k = 0; k < 5; ++k) {
        const int p = k * 320 + threadIdx.x;
        const float4   wv   = cwb[p];
        const unsigned base = cbb[p];
        #pragma unroll
        for (int cc = 0; cc < CH; ++cc) {
            const float* ip = &img[cc * IMS + base];
            const float r = wv.x * ip[0]  + wv.y * ip[1]
                          + wv.z * ip[PW] + wv.w * ip[PW + 1];
            __builtin_nontemporal_store(r, &dstb[(size_t)cc * NHW + p]);
        }
    }
}

// ---------------------------------------------------------------------------
// Fallback sampler (round-1 style) if ws_size is too small for coeffs.
// ---------------------------------------------------------------------------
__global__ __launch_bounds__(256) void sample_kernel(
    const float* __restrict__ feats,
    const float* __restrict__ Mbuf,
    float* __restrict__ out)
{
    __shared__ __align__(16) float img[NHW];
    __shared__ float Ml[NWIN * 6];

    const int bc = blockIdx.x;
    const int b  = bc >> 8;

    const float4* src4 = (const float4*)(feats + (size_t)bc * NHW);
    for (int i = threadIdx.x; i < NHW / 4; i += 256) {
        float4 v = src4[i];
        const int j = i % (NW / 4);
        if (j < 7)      { v.x *= 2.f; v.y *= 2.f; v.z *= 2.f; v.w *= 2.f; }
        else if (j == 7){ v.x *= 2.f; v.y *= 2.f; v.z += 1e-5f; v.w += 1e-5f; }
        else            { v.x += 1e-5f; v.y += 1e-5f; v.z += 1e-5f; v.w += 1e-5f; }
        ((float4*)img)[i] = v;
    }
    for (int i = threadIdx.x; i < NWIN * 6; i += 256)
        Ml[i] = Mbuf[b * NWIN * 6 + i];
    __syncthreads();

    float* dst = out + (size_t)bc * NHW;
    for (int idx = threadIdx.x; idx < NHW; idx += 256) {
        const int h  = idx / NW;
        const int w  = idx - h * NW;
        const int wh = h / 5, ii = h - wh * 5;
        const int ww = w / 5, jj = w - ww * 5;
        const float* m = &Ml[(wh * 8 + ww) * 6];

        const float wcx = (float)(jj - 2) * (2.0f / 39.0f);
        const float wcy = (float)(ii - 2) * (2.0f / 39.0f);
        const float gx = m[0] * wcx + m[1] * wcy + m[2];
        const float gy = m[3] * wcx + m[4] * wcy + m[5];

        float x = (gx + 1.0f) * 19.5f;
        float y = (gy + 1.0f) * 19.5f;
        x = fminf(fmaxf(x, -1.0e6f), 1.0e6f);
        y = fminf(fmaxf(y, -1.0e6f), 1.0e6f);

        const float x0f = floorf(x), y0f = floorf(y);
        const int x0 = (int)x0f, y0 = (int)y0f;
        const int x1 = x0 + 1,  y1 = y0 + 1;
        const float fx = x - x0f, fy = y - y0f;

        const bool xv0 = (x0 >= 0) & (x0 <= NW - 1);
        const bool xv1 = (x1 >= 0) & (x1 <= NW - 1);
        const bool yv0 = (y0 >= 0) & (y0 <= NH - 1);
        const bool yv1 = (y1 >= 0) & (y1 <= NH - 1);

        const int xc0 = min(max(x0, 0), NW - 1);
        const int xc1 = min(max(x1, 0), NW - 1);
        const int yc0 = min(max(y0, 0), NH - 1);
        const int yc1 = min(max(y1, 0), NH - 1);

        float acc = 0.f;
        acc += img[yc0 * NW + xc0] * ((1.f - fx) * (1.f - fy)) * (float)(xv0 && yv0);
        acc += img[yc0 * NW + xc1] * (fx * (1.f - fy)) * (float)(xv1 && yv0);
        acc += img[yc1 * NW + xc0] * ((1.f - fx) * fy) * (float)(xv0 && yv1);
        acc += img[yc1 * NW + xc1] * (fx * fy) * (float)(xv1 && yv1);

        dst[idx] = acc;
    }
}

// ---------------------------------------------------------------------------
extern "C" void kernel_launch(void* const* d_in, const int* in_sizes, int n_in,
                              void* d_out, int out_size, void* d_ws, size_t ws_size,
                              hipStream_t stream)
{
    (void)in_sizes; (void)n_in; (void)out_size;

    const float* feats = (const float*)d_in[0];
    // d_in[1..8] (w1,b1,g1,be1,rm1,rv1,w2,b2) are dead code in the reference.
    const float* gd  = (const float*)d_in[9];
    const float* bed = (const float*)d_in[10];
    const float* rmd = (const float*)d_in[11];
    const float* rvd = (const float*)d_in[12];
    const float* wd  = (const float*)d_in[13];
    const float* bd  = (const float*)d_in[14];

    float* out = (float*)d_out;

    // pooled (4 MB) staged in the front of d_out — fully overwritten by the
    // sample kernel afterwards (stream-ordered).
    float* pooled = out;

    // d_ws layout: Mbuf [96 KB] | cw4 [1.6 MB, 16B-aligned] | cbase [0.4 MB]
    const size_t CW_OFF = 98304;
    const size_t CW_B   = (size_t)NB * NHW * sizeof(float4);          // 1638400
    const size_t CB_OFF = CW_OFF + CW_B;                              // 1736704
    const size_t CB_B   = (size_t)NB * NHW * sizeof(unsigned);        // 409600
    const bool fast = (ws_size >= CB_OFF + CB_B);

    float*    Mbuf  = (float*)d_ws;
    float4*   cw4   = fast ? (float4*)((char*)d_ws + CW_OFF)   : nullptr;
    unsigned* cbase = fast ? (unsigned*)((char*)d_ws + CB_OFF) : nullptr;

    pool_bn_kernel<<<NB * NC_, 256, 0, stream>>>(feats, gd, bed, rmd, rvd, pooled);
    co_M_kernel<<<NB * NWIN, 256, 0, stream>>>(pooled, wd, bd, Mbuf, cw4, cbase);
    if (fast)
        sample_pad_kernel<<<NB * (NC_ / CH), 320, 0, stream>>>(feats, cw4, cbase, out);
    else
        sample_kernel<<<NB * NC_, 256, 0, stream>>>(feats, Mbuf, out);
}